// Round 7
// baseline (246.642 us; speedup 1.0000x reference)
//
#include <hip/hip_runtime.h>

// BinarizeLinear: out[65536,1024] = x @ sign(W)^T + bias
// Round 7: depth-2 A prefetch + counted-wait raw barriers + frag-linear LDS.
// 128x256 tile, BK=32, 8 waves (2Mx4N), per-wave 64x64 out. LDS 48 KB
// (A 2x8KB frag-linear, B 2x16KB frag-linear) -> 2 blocks/CU, 4 waves/SIMD.
// A (x fp32): global->reg (issued 2 K-steps ahead, covers ~900cyc HBM lat),
// fused fp32->bf16 cvt, 1 ds_write_b128/thread (contiguous per wave).
// B: prepassed sign(W) bf16 frag-image in d_ws, gload_lds 1 step ahead.
// Per-iter sync: lgkmcnt(0) + vmcnt(2) + s_barrier (deep A loads stay live).

typedef __bf16 bf16x8 __attribute__((ext_vector_type(8)));
typedef float  f32x4  __attribute__((ext_vector_type(4)));

constexpr int Mdim = 65536, Ndim = 1024, Kdim = 1024;
constexpr int BM = 128, BN = 256, BK = 32;
constexpr int NKT = Kdim / BK;                    // 32
constexpr int NWG = (Mdim / BM) * (Ndim / BN);    // 2048

typedef const __attribute__((address_space(1))) char ga_char;
typedef __attribute__((address_space(3))) char lds_char;
__device__ __forceinline__ void gload16(const void* g, void* l) {
    __builtin_amdgcn_global_load_lds((ga_char*)g, (lds_char*)l, 16, 0, 0);
}
__device__ __forceinline__ f32x4 mfma16(bf16x8 a, bf16x8 b, f32x4 c) {
    return __builtin_amdgcn_mfma_f32_16x16x32_bf16(a, b, c, 0, 0, 0);
}
#define SBARRIER()   asm volatile("s_barrier" ::: "memory")
#define WAIT_LGKM0() asm volatile("s_waitcnt lgkmcnt(0)" ::: "memory")
#define WAIT_VM2()   asm volatile("s_waitcnt vmcnt(2)" ::: "memory")

// ---- prepass: sign(W) -> bf16, frag-linear image (same as R6) ----
// WS[(((colb*32+kt)*16+nb)*64+lane)*8+e] =
//   sign(W[colb*256 + nb*16 + (lane&15)][kt*32 + (lane>>4)*8 + e])
__global__ __launch_bounds__(256)
void wprep_kernel(const float* __restrict__ W, __bf16* __restrict__ WS) {
    const int id   = blockIdx.x * 256 + threadIdx.x;   // 131072
    const int colb = id >> 15;
    const int kt   = (id >> 10) & 31;
    const int g    = id & 1023;
    const int nb   = g >> 6;
    const int lane = g & 63;
    const int row  = colb * 256 + nb * 16 + (lane & 15);
    const int col  = kt * 32 + (lane >> 4) * 8;
    const float* src = W + (size_t)row * Kdim + col;
    f32x4 a = *(const f32x4*)src;
    f32x4 b = *(const f32x4*)(src + 4);
    bf16x8 o;
#pragma unroll
    for (int e = 0; e < 4; ++e) {
        o[e]     = (__bf16)(float)((a[e] > 0.f) - (a[e] < 0.f));
        o[e + 4] = (__bf16)(float)((b[e] > 0.f) - (b[e] < 0.f));
    }
    *(bf16x8*)(WS + (size_t)id * 8) = o;
}

// ---- main GEMM ----
__global__ __launch_bounds__(512, 4)
void binlin_d2(const float* __restrict__ X, const __bf16* __restrict__ WS,
               const float* __restrict__ bias, float* __restrict__ out)
{
    __shared__ __align__(16) __bf16 Al[2][BM * BK];   // 2 x 8 KB, frag-linear
    __shared__ __align__(16) __bf16 Bl[2][BN * BK];   // 2 x 16 KB, frag-linear

    // T1: bijective chunked XCD swizzle (2048 % 8 == 0), colb fastest
    const int swz  = (blockIdx.x & 7) * (NWG / 8) + (blockIdx.x >> 3);
    const int colb = swz & 3;
    const int rowb = swz >> 2;
    const int row0 = rowb * BM;

    const int tid  = threadIdx.x;
    const int lane = tid & 63;
    const int wid  = tid >> 6;         // 0..7
    const int wr   = wid >> 2;         // M half (64 rows)
    const int wcn  = wid & 3;          // N quarter (64 cols)
    const int fr   = lane & 15;
    const int hq   = lane >> 4;        // 0..3

    // A staging: thread t covers frag slot (mb = t>>6, lane): reads
    // x[row0 + mb*16 + (lane&15)][kt*32 + (lane>>4)*8 .. +8]
    const float* Xs = X + (size_t)(row0 + wid * 16 + fr) * Kdim + hq * 8;
    // A LDS dest (frag-linear, wave-contiguous): elems (wid*64 + lane)*8
    const int a_dst = (wid * 64 + lane) * 8;

    const __bf16* WSb = WS + (size_t)colb * 262144;

    f32x4 rA[2][2];                    // 2-deep A prefetch
    auto GLA = [&](int kt, int s) {
        const float* p = Xs + kt * BK;
        rA[s][0] = *(const f32x4*)p;
        rA[s][1] = *(const f32x4*)(p + 4);
    };
    auto DSWA = [&](int buf, int s) {  // fused cvt + one ds_write_b128
        bf16x8 v;
#pragma unroll
        for (int e = 0; e < 4; ++e) {
            v[e]     = (__bf16)rA[s][0][e];
            v[e + 4] = (__bf16)rA[s][1][e];
        }
        *(bf16x8*)(&Al[buf][a_dst]) = v;
    };
    auto GLB = [&](int buf, int kt) {  // 2 x gload16/thread, 16 KB tile
        const __bf16* s = WSb + (size_t)kt * 8192 + wid * 1024 + lane * 8;
        gload16(s,       &Bl[buf][wid * 1024]);
        gload16(s + 512, &Bl[buf][wid * 1024 + 512]);
    };

    auto lda = [&](int buf, int i) -> bf16x8 {   // contiguous 1KB per wave
        return *(const bf16x8*)(&Al[buf][((wr * 4 + i) * 64 + lane) * 8]);
    };
    auto ldb = [&](int buf, int j) -> bf16x8 {   // contiguous 1KB per wave
        return *(const bf16x8*)(&Bl[buf][((wcn * 4 + j) * 64 + lane) * 8]);
    };

    f32x4 acc[4][4] = {};

    // prologue: B(0) oldest, then A(0), A(1); DSWA(0) auto-waits A(0);
    // full drain once (one-time cost), buffers published.
    GLB(0, 0);
    GLA(0, 0);
    GLA(1, 1);
    DSWA(0, 0);
    __syncthreads();

    for (int t = 0; t < NKT; ++t) {
        const int cur = t & 1;
        const int nxt = cur ^ 1;
        const int tB  = (t + 1 < NKT) ? t + 1 : NKT - 1;   // clamp: uniform
        const int tA  = (t + 2 < NKT) ? t + 2 : NKT - 1;   // counts every iter

        GLB(nxt, tB);        // 2 gload_lds (oldest in-flight this iter)
        GLA(tA, cur);        // 2 dwordx4 (youngest; stays live past barrier)

        bf16x8 af[4];
#pragma unroll
        for (int i = 0; i < 4; ++i) af[i] = lda(cur, i);
        __builtin_amdgcn_s_setprio(1);
#pragma unroll
        for (int j = 0; j < 4; ++j) {
            bf16x8 bf = ldb(cur, j);
#pragma unroll
            for (int i = 0; i < 4; ++i)
                acc[i][j] = mfma16(af[i], bf, acc[i][j]);
        }
        __builtin_amdgcn_s_setprio(0);

        DSWA(nxt, nxt);      // consumes tile t+1 regs (issued iter t-1,
                             // auto vmcnt(4) — a full iteration of cover)
        WAIT_LGKM0();        // my ds_write visible
        WAIT_VM2();          // my 2 gload_lds done; 2 deep-A loads stay out
        __builtin_amdgcn_sched_barrier(0);
        SBARRIER();          // publish buf[nxt]
    }

    // epilogue: C row = i*16 + hq*4 + r, col = j*16 + fr
    const int orow = row0 + wr * 64 + hq * 4;
    const int ocol = colb * BN + wcn * 64 + fr;
#pragma unroll
    for (int j = 0; j < 4; ++j) {
        const float bv = bias[ocol + j * 16];
#pragma unroll
        for (int i = 0; i < 4; ++i)
#pragma unroll
            for (int r = 0; r < 4; ++r)
                out[(size_t)(orow + i * 16 + r) * Ndim + (ocol + j * 16)] =
                    acc[i][j][r] + bv;
    }
}

// ---- fallback (ws too small): reg-staged 128x128, inline sign ----
__global__ __launch_bounds__(256)
void binlin_fallback(const float* __restrict__ X, const float* __restrict__ Wf,
                     const float* __restrict__ bias, float* __restrict__ out)
{
    __shared__ __align__(16) __bf16 Al[2][128][32];
    __shared__ __align__(16) __bf16 Bl[2][128][32];
    constexpr int NT = Kdim / 32;
    const int swz  = (blockIdx.x & 7) * (4096 / 8) + (blockIdx.x >> 3);
    const int colb = swz & 7, rowb = swz >> 3;
    const int row0 = rowb * 128, col0 = colb * 128;
    const int tid = threadIdx.x, lane = tid & 63, wid = tid >> 6;
    const int wr = wid >> 1, wc = wid & 1;
    const int sr = tid >> 2, sc = (tid & 3) * 8;
    const float* Xb = X + (size_t)row0 * Kdim;
    const float* Wb = Wf + (size_t)col0 * Kdim;
    f32x4 ra[2][2], rb[2][2];
    auto GL = [&](int k0) {
#pragma unroll
        for (int p = 0; p < 2; ++p) {
            const float* sa = Xb + (size_t)(p * 64 + sr) * Kdim + k0 + sc;
            ra[p][0] = *(const f32x4*)sa; ra[p][1] = *(const f32x4*)(sa + 4);
            const float* sb = Wb + (size_t)(p * 64 + sr) * Kdim + k0 + sc;
            rb[p][0] = *(const f32x4*)sb; rb[p][1] = *(const f32x4*)(sb + 4);
        }
    };
    auto DSW = [&](int buf) {
#pragma unroll
        for (int p = 0; p < 2; ++p) {
            bf16x8 va, vb;
#pragma unroll
            for (int e = 0; e < 4; ++e) {
                va[e] = (__bf16)ra[p][0][e]; va[e + 4] = (__bf16)ra[p][1][e];
                float a = rb[p][0][e], b = rb[p][1][e];
                vb[e] = (__bf16)(float)((a > 0.f) - (a < 0.f));
                vb[e + 4] = (__bf16)(float)((b > 0.f) - (b < 0.f));
            }
            *(bf16x8*)&Al[buf][p * 64 + sr][sc] = va;
            *(bf16x8*)&Bl[buf][p * 64 + sr][sc] = vb;
        }
    };
    f32x4 acc[4][4] = {};
    const int fr = lane & 15, ks = (lane >> 4) * 8;
    auto COMP = [&](int buf) {
        bf16x8 af[4], bf[4];
#pragma unroll
        for (int i = 0; i < 4; ++i) af[i] = *(const bf16x8*)&Al[buf][wr * 64 + fr + i * 16][ks];
#pragma unroll
        for (int j = 0; j < 4; ++j) bf[j] = *(const bf16x8*)&Bl[buf][wc * 64 + fr + j * 16][ks];
#pragma unroll
        for (int i = 0; i < 4; ++i)
#pragma unroll
            for (int j = 0; j < 4; ++j)
                acc[i][j] = mfma16(af[i], bf[j], acc[i][j]);
    };
    GL(0); DSW(0); __syncthreads();
    int cur = 0;
    for (int t = 0; t < NT; ++t) {
        if (t + 1 < NT) GL((t + 1) * 32);
        COMP(cur);
        if (t + 1 < NT) { DSW(cur ^ 1); __syncthreads(); cur ^= 1; }
    }
    const int orow = row0 + wr * 64 + (lane >> 4) * 4;
    const int ocol = col0 + wc * 64 + fr;
#pragma unroll
    for (int j = 0; j < 4; ++j) {
        const float bv = bias[ocol + j * 16];
#pragma unroll
        for (int i = 0; i < 4; ++i)
#pragma unroll
            for (int r = 0; r < 4; ++r)
                out[(size_t)(orow + i * 16 + r) * Ndim + (ocol + j * 16)] = acc[i][j][r] + bv;
    }
}

extern "C" void kernel_launch(void* const* d_in, const int* in_sizes, int n_in,
                              void* d_out, int out_size, void* d_ws, size_t ws_size,
                              hipStream_t stream) {
    const float* x  = (const float*)d_in[0];
    const float* w  = (const float*)d_in[1];
    const float* b  = (const float*)d_in[2];
    float* out      = (float*)d_out;

    constexpr size_t WS_BYTES = (size_t)Ndim * Kdim * sizeof(__bf16);  // 2 MB

    if (ws_size >= WS_BYTES) {
        __bf16* ws = (__bf16*)d_ws;
        wprep_kernel<<<dim3(512), dim3(256), 0, stream>>>(w, ws);
        binlin_d2<<<dim3(NWG), dim3(512), 0, stream>>>(x, ws, b, out);
    } else {
        binlin_fallback<<<dim3(4096), dim3(256), 0, stream>>>(x, w, b, out);
    }
}